// Round 5
// baseline (1534.261 us; speedup 1.0000x reference)
//
#include <hip/hip_runtime.h>
#include <hip/hip_bf16.h>
#include <stdint.h>

#define M_TOTAL 8192      // BATCH*SEQ = 4*2048
#define N_TOTAL 16384     // OUT_FEATURES
#define K_TOTAL 4096      // IN_FEATURES (== BLOCKSIZE -> absmax is per output row)

#define BM 128
#define BN 128
#define BK 32

using f32x4  = __attribute__((ext_vector_type(4))) float;
using bf16x8 = __attribute__((ext_vector_type(8))) short;   // 8 bf16 in 4 VGPRs

__device__ __forceinline__ unsigned short f2bf(float f) {
    union { float f; unsigned u; } v; v.f = f;
    unsigned r = v.u + 0x7fffu + ((v.u >> 16) & 1u);   // RNE
    return (unsigned short)(r >> 16);
}

__device__ __forceinline__ void gload_lds16(const void* g, void* l) {
    __builtin_amdgcn_global_load_lds(
        (const __attribute__((address_space(1))) unsigned int*)g,
        (__attribute__((address_space(3))) unsigned int*)l,
        16, 0, 0);
}

// ---------------- dequant W: wb[o*K+i] = bf16(code[q[o*K+i]] * absmax[o]) ----------
__global__ void dequant_w_kernel(const int* __restrict__ q,
                                 const float* __restrict__ am,
                                 const float* __restrict__ code,
                                 unsigned short* __restrict__ wb) {
    __shared__ float lc[256];
    if (threadIdx.x < 256) lc[threadIdx.x] = code[threadIdx.x];
    __syncthreads();
    const int total = (N_TOTAL / 4) * K_TOTAL;   // int4 groups: 16,777,216
    const int stride = gridDim.x * blockDim.x;
    for (int i = blockIdx.x * blockDim.x + threadIdx.x; i < total; i += stride) {
        int4 v = reinterpret_cast<const int4*>(q)[i];
        float a = am[i >> 10];                   // (i*4) >> 12 : one block == one row
        ushort4 o;
        o.x = f2bf(lc[v.x & 255] * a);
        o.y = f2bf(lc[v.y & 255] * a);
        o.z = f2bf(lc[v.z & 255] * a);
        o.w = f2bf(lc[v.w & 255] * a);
        reinterpret_cast<ushort4*>(wb)[i] = o;
    }
}

// ---------------- convert x fp32 -> bf16 ----------------
__global__ void cvt_x_kernel(const float* __restrict__ x,
                             unsigned short* __restrict__ xb) {
    const int total = (M_TOTAL * K_TOTAL) / 4;   // 8,388,608 float4 groups
    const int stride = gridDim.x * blockDim.x;
    for (int i = blockIdx.x * blockDim.x + threadIdx.x; i < total; i += stride) {
        float4 v = reinterpret_cast<const float4*>(x)[i];
        ushort4 o;
        o.x = f2bf(v.x); o.y = f2bf(v.y); o.z = f2bf(v.z); o.w = f2bf(v.w);
        reinterpret_cast<ushort4*>(xb)[i] = o;
    }
}

// ---------------- GEMM: C[M][N] = A[M][K] * B[N][K]^T + bias, bf16 in / f32 out ----
__global__ __launch_bounds__(256) void gemm_bias_kernel(
        const unsigned short* __restrict__ A,   // [M][K] bf16
        const unsigned short* __restrict__ B,   // [N][K] bf16 (row o = output feature)
        const float* __restrict__ bias,         // [N]
        float* __restrict__ C) {                // [M][N] f32
    __shared__ __align__(16) unsigned short sA[BM * BK];   // 8 KB
    __shared__ __align__(16) unsigned short sB[BN * BK];   // 8 KB

    // XCD-aware swizzle (nwg = 8192, divisible by 8 -> bijective)
    const int nwg = gridDim.x;
    const int bid = blockIdx.x;
    const int wg  = (bid & 7) * (nwg >> 3) + (bid >> 3);

    const int nbn  = N_TOTAL / BN;          // 128
    const int brow = (wg / nbn) * BM;
    const int bcol = (wg % nbn) * BN;

    const int tid  = threadIdx.x;
    const int wid  = tid >> 6;              // 0..3
    const int lane = tid & 63;
    const int wr   = wid >> 1;              // wave row (0..1) -> 64 rows
    const int wc   = wid & 1;               // wave col (0..1) -> 64 cols

    // staging: wave wid stages chunks {wid, wid+4} of each tile.
    // chunk c = 16 rows of the [128][32] tile = 1024 B = one wave-issue (64 lanes x 16 B)
    const int c0 = wid, c1 = wid + 4;
    const int lrow = lane >> 2;             // 0..15 row within chunk
    const int lcol = (lane & 3) * 8;        // 8-elem column group

    const unsigned short* a0 = A + (long long)(brow + c0 * 16 + lrow) * K_TOTAL + lcol;
    const unsigned short* a1 = A + (long long)(brow + c1 * 16 + lrow) * K_TOTAL + lcol;
    const unsigned short* b0 = B + (long long)(bcol + c0 * 16 + lrow) * K_TOTAL + lcol;
    const unsigned short* b1 = B + (long long)(bcol + c1 * 16 + lrow) * K_TOTAL + lcol;

    unsigned short* sA0 = &sA[c0 * 512];
    unsigned short* sA1 = &sA[c1 * 512];
    unsigned short* sB0 = &sB[c0 * 512];
    unsigned short* sB1 = &sB[c1 * 512];

    f32x4 acc[4][4];
#pragma unroll
    for (int m = 0; m < 4; ++m)
#pragma unroll
        for (int n = 0; n < 4; ++n) acc[m][n] = (f32x4){0.f, 0.f, 0.f, 0.f};

    const int arow  = wr * 64 + (lane & 15);   // + m*16 : A-frag row in tile
    const int brow2 = wc * 64 + (lane & 15);   // + n*16 : B-frag row (=out col) in tile
    const int koff  = (lane >> 4) * 8;         // 8 contiguous k per lane

    for (int k0 = 0; k0 < K_TOTAL; k0 += BK) {
        gload_lds16(a0 + k0, sA0);
        gload_lds16(a1 + k0, sA1);
        gload_lds16(b0 + k0, sB0);
        gload_lds16(b1 + k0, sB1);
        __syncthreads();   // compiler drains vmcnt before barrier -> staging visible

        bf16x8 af[4], bf[4];
#pragma unroll
        for (int m = 0; m < 4; ++m)
            af[m] = *reinterpret_cast<const bf16x8*>(&sA[(arow + m * 16) * BK + koff]);
#pragma unroll
        for (int n = 0; n < 4; ++n)
            bf[n] = *reinterpret_cast<const bf16x8*>(&sB[(brow2 + n * 16) * BK + koff]);
#pragma unroll
        for (int m = 0; m < 4; ++m)
#pragma unroll
            for (int n = 0; n < 4; ++n)
                acc[m][n] = __builtin_amdgcn_mfma_f32_16x16x32_bf16(af[m], bf[n], acc[m][n], 0, 0, 0);
        __syncthreads();   // all reads done before next-iter staging overwrites
    }

    // epilogue: C/D layout col = lane&15, row = (lane>>4)*4 + r  [m89-verified]
    float bv[4];
#pragma unroll
    for (int n = 0; n < 4; ++n)
        bv[n] = bias[bcol + wc * 64 + n * 16 + (lane & 15)];
#pragma unroll
    for (int m = 0; m < 4; ++m) {
        const int row0 = brow + wr * 64 + m * 16 + (lane >> 4) * 4;
#pragma unroll
        for (int n = 0; n < 4; ++n) {
            const int col = bcol + wc * 64 + n * 16 + (lane & 15);
#pragma unroll
            for (int r = 0; r < 4; ++r)
                C[(long long)(row0 + r) * N_TOTAL + col] = acc[m][n][r] + bv[n];
        }
    }
}

extern "C" void kernel_launch(void* const* d_in, const int* in_sizes, int n_in,
                              void* d_out, int out_size, void* d_ws, size_t ws_size,
                              hipStream_t stream) {
    const float* x      = (const float*)d_in[0];   // [4,2048,4096] f32
    const int*   wq     = (const int*)  d_in[1];   // [16384,4096] int32 idx
    const float* absmax = (const float*)d_in[2];   // [16384]
    const float* code   = (const float*)d_in[3];   // [256]
    const float* bias   = (const float*)d_in[4];   // [16384]
    float* out = (float*)d_out;                    // [4,2048,16384] f32

    // workspace: W bf16 (134.2 MB) then x bf16 (67.1 MB)
    unsigned short* wb = (unsigned short*)d_ws;
    unsigned short* xb = wb + (size_t)N_TOTAL * K_TOTAL;

    dequant_w_kernel<<<2048, 256, 0, stream>>>(wq, absmax, code, wb);
    cvt_x_kernel   <<<2048, 256, 0, stream>>>(x, xb);

    dim3 grid((M_TOTAL / BM) * (N_TOTAL / BN));    // 8192 blocks
    gemm_bias_kernel<<<grid, 256, 0, stream>>>(xb, wb, bias, out);
}

// Round 6
// 1231.059 us; speedup vs baseline: 1.2463x; 1.2463x over previous
//
#include <hip/hip_runtime.h>
#include <hip/hip_bf16.h>
#include <stdint.h>

#define M_TOTAL 8192      // BATCH*SEQ
#define N_TOTAL 16384     // OUT_FEATURES
#define K_TOTAL 4096      // IN_FEATURES (== BLOCKSIZE -> absmax is per output row)

#define BM 256
#define BN 256
#define BK 64
#define NKT (K_TOTAL / BK)   // 64 K-tiles

using f32x4  = __attribute__((ext_vector_type(4))) float;
using bf16x8 = __attribute__((ext_vector_type(8))) short;

#define UNROLL _Pragma("unroll")

__device__ __forceinline__ unsigned short f2bf(float f) {
    union { float f; unsigned u; } v; v.f = f;
    unsigned r = v.u + 0x7fffu + ((v.u >> 16) & 1u);   // RNE
    return (unsigned short)(r >> 16);
}

__device__ __forceinline__ void gload_lds16(const void* g, void* l) {
    __builtin_amdgcn_global_load_lds(
        (const __attribute__((address_space(1))) unsigned int*)g,
        (__attribute__((address_space(3))) unsigned int*)l,
        16, 0, 0);
}

// ---------------- dequant W: wb[o*K+i] = bf16(code[q[o*K+i]] * absmax[o]) ----------
__global__ void dequant_w_kernel(const int* __restrict__ q,
                                 const float* __restrict__ am,
                                 const float* __restrict__ code,
                                 unsigned short* __restrict__ wb) {
    __shared__ float lc[256];
    if (threadIdx.x < 256) lc[threadIdx.x] = code[threadIdx.x];
    __syncthreads();
    const int total = (N_TOTAL / 4) * K_TOTAL;   // 16,777,216 int4 groups
    const int stride = gridDim.x * blockDim.x;
    for (int i = blockIdx.x * blockDim.x + threadIdx.x; i < total; i += stride) {
        int4 v = reinterpret_cast<const int4*>(q)[i];
        float a = am[i >> 10];                   // one quant block == one weight row
        ushort4 o;
        o.x = f2bf(lc[v.x & 255] * a);
        o.y = f2bf(lc[v.y & 255] * a);
        o.z = f2bf(lc[v.z & 255] * a);
        o.w = f2bf(lc[v.w & 255] * a);
        reinterpret_cast<ushort4*>(wb)[i] = o;
    }
}

// ---------------- convert x fp32 -> bf16 ----------------
__global__ void cvt_x_kernel(const float* __restrict__ x,
                             unsigned short* __restrict__ xb) {
    const int total = (M_TOTAL * K_TOTAL) / 4;
    const int stride = gridDim.x * blockDim.x;
    for (int i = blockIdx.x * blockDim.x + threadIdx.x; i < total; i += stride) {
        float4 v = reinterpret_cast<const float4*>(x)[i];
        ushort4 o;
        o.x = f2bf(v.x); o.y = f2bf(v.y); o.z = f2bf(v.z); o.w = f2bf(v.w);
        reinterpret_cast<ushort4*>(xb)[i] = o;
    }
}

// ---------------- GEMM 256x256x64, 8-phase, swizzled LDS (m201 template) ----------
// ds-load frag macros: logical slot = ks*4 + (lane>>4); physical = ^ (lane&7)
#define LOAD_A(BUFI, MH)                                                          \
    UNROLL for (int mf = 0; mf < 4; ++mf)                                         \
        UNROLL for (int ks = 0; ks < 2; ++ks)                                     \
            a_r[mf][ks] = *reinterpret_cast<const bf16x8*>(                       \
                &sA[BUFI][((MH)*128 + arow_base + mf*16)*BK +                     \
                          (((ks*4 + rslot_hi) ^ rslot_xor)*8)]);

#define LOAD_B(BUFI, NH)                                                          \
    UNROLL for (int nf = 0; nf < 2; ++nf)                                         \
        UNROLL for (int ks = 0; ks < 2; ++ks)                                     \
            b_r[nf][ks] = *reinterpret_cast<const bf16x8*>(                       \
                &sB[BUFI][((NH)*128 + brow_base + nf*16)*BK +                     \
                          (((ks*4 + rslot_hi) ^ rslot_xor)*8)]);

#define DO_MFMA(MH, NH)                                                           \
    UNROLL for (int mf = 0; mf < 4; ++mf)                                         \
        UNROLL for (int nf = 0; nf < 2; ++nf) {                                   \
            acc[MH][mf][NH][nf] = __builtin_amdgcn_mfma_f32_16x16x32_bf16(        \
                a_r[mf][0], b_r[nf][0], acc[MH][mf][NH][nf], 0, 0, 0);            \
            acc[MH][mf][NH][nf] = __builtin_amdgcn_mfma_f32_16x16x32_bf16(        \
                a_r[mf][1], b_r[nf][1], acc[MH][mf][NH][nf], 0, 0, 0);            \
        }

#define PHASE_MID()                                                               \
    __builtin_amdgcn_s_barrier();                                                 \
    asm volatile("s_waitcnt lgkmcnt(0)" ::: "memory");                            \
    __builtin_amdgcn_sched_barrier(0);                                            \
    __builtin_amdgcn_s_setprio(1);

#define PHASE_END()                                                               \
    __builtin_amdgcn_s_setprio(0);                                                \
    __builtin_amdgcn_s_barrier();

__global__ __launch_bounds__(512, 2) void gemm8_kernel(
        const unsigned short* __restrict__ A,   // [M][K] bf16
        const unsigned short* __restrict__ B,   // [N][K] bf16
        const float* __restrict__ bias,         // [N]
        float* __restrict__ C) {                // [M][N] f32
    __shared__ __align__(16) unsigned short sA[2][BM * BK];   // 2 x 32 KB
    __shared__ __align__(16) unsigned short sB[2][BN * BK];   // 2 x 32 KB

    // XCD swizzle (nwg = 2048, % 8 == 0 -> bijective)
    const int nwg = gridDim.x;
    const int bid = blockIdx.x;
    const int wg  = (bid & 7) * (nwg >> 3) + (bid >> 3);
    const int nbn = N_TOTAL / BN;            // 64
    const int brow = (wg / nbn) * BM;
    const int bcol = (wg % nbn) * BN;

    const int tid  = threadIdx.x;
    const int wid  = tid >> 6;               // 0..7
    const int lane = tid & 63;
    const int wm   = wid >> 2;               // 0..1  (M-waves)
    const int wn   = wid & 3;                // 0..3  (N-waves)

    // ---- staging constants: linear LDS dest + pre-swizzled global source ----
    // issue(h,j) covers tile rows [h*128+j*64, +64); wave wid owns 8 rows.
    const int srow = wid * 8 + (lane >> 3);                 // row within issue
    const int scol = ((lane & 7) ^ (lane >> 3)) * 8;        // pre-swizzled col (elems)
    const unsigned short* Asrc = A + (long long)(brow + srow) * K_TOTAL + scol;
    const unsigned short* Bsrc = B + (long long)(bcol + srow) * K_TOTAL + scol;

    auto stA = [&](int h, int j, int kt, int b) {
        gload_lds16(Asrc + (long long)(h*128 + j*64) * K_TOTAL + kt*BK,
                    &sA[b][(h*128 + j*64)*BK + wid*512]);
    };
    auto stB = [&](int h, int j, int kt, int b) {
        gload_lds16(Bsrc + (long long)(h*128 + j*64) * K_TOTAL + kt*BK,
                    &sB[b][(h*128 + j*64)*BK + wid*512]);
    };

    // ---- ds-read constants (swizzled read side of the involution) ----
    const int arow_base = wm * 64 + (lane & 15);   // + mh*128 + mf*16
    const int brow_base = wn * 32 + (lane & 15);   // + nh*128 + nf*16
    const int rslot_hi  = lane >> 4;
    const int rslot_xor = lane & 7;

    f32x4 acc[2][4][2][2];
    UNROLL for (int mh = 0; mh < 2; ++mh)
        UNROLL for (int mf = 0; mf < 4; ++mf)
            UNROLL for (int nh = 0; nh < 2; ++nh)
                UNROLL for (int nf = 0; nf < 2; ++nf)
                    acc[mh][mf][nh][nf] = (f32x4){0.f, 0.f, 0.f, 0.f};

    bf16x8 a_r[4][2];
    bf16x8 b_r[2][2];

    // ---- prologue: tile0 full -> buf0; Ah0(1), Bh1(1) -> buf1 (12 loads/wave) ----
    stA(0,0,0,0); stA(0,1,0,0); stA(1,0,0,0); stA(1,1,0,0);
    stB(0,0,0,0); stB(0,1,0,0); stB(1,0,0,0); stB(1,1,0,0);
    stA(0,0,1,1); stA(0,1,1,1);
    stB(1,0,1,1); stB(1,1,1,1);
    asm volatile("s_waitcnt vmcnt(4)" ::: "memory");   // tile0 landed
    __builtin_amdgcn_s_barrier();

    // ---- main loop: 2 K-tiles / iteration, 8 phases ----
    // quadrant order per tile: (0,0) (0,1) (1,1) (1,0)
    // stage plan: ph1 Ah1(t+1)->b1, ph2 Bh0(t+1)->b1, ph3 Ah0(t+2)->b0,
    //             ph4 Bh1(t+2)->b0, ph5 Ah1(t+2)->b0, ph6 Bh0(t+2)->b0,
    //             ph7 Ah0(t+3)->b1, ph8 Bh1(t+3)->b1.  vmcnt(4) at ph4, ph8.
    for (int it = 0; it < NKT/2; ++it) {
        const int t   = 2*it;
        const int tp1 = t + 1;
        const int p2  = (t+2 < NKT) ? t+2 : NKT-1;   // tail: redundant reload, unread
        const int p3  = (t+3 < NKT) ? t+3 : NKT-1;

        // ph1 (buf0, tile t, quad 0,0)
        LOAD_A(0, 0); LOAD_B(0, 0);
        stA(1,0,tp1,1); stA(1,1,tp1,1);
        PHASE_MID(); DO_MFMA(0, 0); PHASE_END();

        // ph2 (0,1)
        LOAD_B(0, 1);
        stB(0,0,tp1,1); stB(0,1,tp1,1);
        PHASE_MID(); DO_MFMA(0, 1); PHASE_END();

        // ph3 (1,1)
        LOAD_A(0, 1);
        stA(0,0,p2,0); stA(0,1,p2,0);
        PHASE_MID(); DO_MFMA(1, 1); PHASE_END();

        // ph4 (1,0) -- tile t done; ensure tile t+1 (ph1,ph2 loads) landed
        LOAD_B(0, 0);
        stB(1,0,p2,0); stB(1,1,p2,0);
        PHASE_MID(); DO_MFMA(1, 0);
        __builtin_amdgcn_s_setprio(0);
        asm volatile("s_waitcnt vmcnt(4)" ::: "memory");
        __builtin_amdgcn_s_barrier();

        // ph5 (buf1, tile t+1, quad 0,0)
        LOAD_A(1, 0); LOAD_B(1, 0);
        stA(1,0,p2,0); stA(1,1,p2,0);
        PHASE_MID(); DO_MFMA(0, 0); PHASE_END();

        // ph6 (0,1)
        LOAD_B(1, 1);
        stB(0,0,p2,0); stB(0,1,p2,0);
        PHASE_MID(); DO_MFMA(0, 1); PHASE_END();

        // ph7 (1,1)
        LOAD_A(1, 1);
        stA(0,0,p3,1); stA(0,1,p3,1);
        PHASE_MID(); DO_MFMA(1, 1); PHASE_END();

        // ph8 (1,0) -- tile t+1 done; ensure tile t+2 (ph5,ph6 loads) landed
        LOAD_B(1, 0);
        stB(1,0,p3,1); stB(1,1,p3,1);
        PHASE_MID(); DO_MFMA(1, 0);
        __builtin_amdgcn_s_setprio(0);
        asm volatile("s_waitcnt vmcnt(4)" ::: "memory");
        __builtin_amdgcn_s_barrier();
    }

    // ---- epilogue: C/D layout col = lane&15, row = (lane>>4)*4 + r ----
    const int crow0 = (lane >> 4) * 4;
    const int ccol  = lane & 15;
    UNROLL for (int mh = 0; mh < 2; ++mh)
        UNROLL for (int mf = 0; mf < 4; ++mf) {
            const long long row0 = (long long)brow + mh*128 + wm*64 + mf*16 + crow0;
            UNROLL for (int nh = 0; nh < 2; ++nh)
                UNROLL for (int nf = 0; nf < 2; ++nf) {
                    const int col = bcol + nh*128 + wn*32 + nf*16 + ccol;
                    const float bv = bias[col];
                    UNROLL for (int r = 0; r < 4; ++r)
                        C[(row0 + r) * N_TOTAL + col] = acc[mh][mf][nh][nf][r] + bv;
                }
        }
}

extern "C" void kernel_launch(void* const* d_in, const int* in_sizes, int n_in,
                              void* d_out, int out_size, void* d_ws, size_t ws_size,
                              hipStream_t stream) {
    const float* x      = (const float*)d_in[0];   // [4,2048,4096] f32
    const int*   wq     = (const int*)  d_in[1];   // [16384,4096] int32 idx
    const float* absmax = (const float*)d_in[2];   // [16384]
    const float* code   = (const float*)d_in[3];   // [256]
    const float* bias   = (const float*)d_in[4];   // [16384]
    float* out = (float*)d_out;                    // [4,2048,16384] f32

    unsigned short* wb = (unsigned short*)d_ws;                    // W bf16 134 MB
    unsigned short* xb = wb + (size_t)N_TOTAL * K_TOTAL;           // x bf16  67 MB

    dequant_w_kernel<<<2048, 256, 0, stream>>>(wq, absmax, code, wb);
    cvt_x_kernel   <<<2048, 256, 0, stream>>>(x, xb);

    dim3 grid((M_TOTAL / BM) * (N_TOTAL / BN));    // 32*64 = 2048 blocks
    gemm8_kernel<<<grid, 512, 0, stream>>>(xb, wb, bias, out);
}

// Round 7
// 1227.566 us; speedup vs baseline: 1.2498x; 1.0028x over previous
//
#include <hip/hip_runtime.h>
#include <hip/hip_bf16.h>
#include <stdint.h>

#define M_TOTAL 8192      // BATCH*SEQ
#define N_TOTAL 16384     // OUT_FEATURES
#define K_TOTAL 4096      // IN_FEATURES (== BLOCKSIZE -> absmax is per output row)

#define BM 256
#define BN 256
#define BK 64
#define NKT (K_TOTAL / BK)   // 64 K-tiles

using f32x4  = __attribute__((ext_vector_type(4))) float;
using bf16x8 = __attribute__((ext_vector_type(8))) short;

#define UNROLL _Pragma("unroll")

__device__ __forceinline__ unsigned short f2bf(float f) {
    union { float f; unsigned u; } v; v.f = f;
    unsigned r = v.u + 0x7fffu + ((v.u >> 16) & 1u);   // RNE
    return (unsigned short)(r >> 16);
}

__device__ __forceinline__ void gload_lds16(const void* g, void* l) {
    __builtin_amdgcn_global_load_lds(
        (const __attribute__((address_space(1))) unsigned int*)g,
        (__attribute__((address_space(3))) unsigned int*)l,
        16, 0, 0);
}

// ---------------- dequant W: wb[o*K+i] = bf16(code[q[o*K+i]] * absmax[o]) ----------
__global__ void dequant_w_kernel(const int* __restrict__ q,
                                 const float* __restrict__ am,
                                 const float* __restrict__ code,
                                 unsigned short* __restrict__ wb) {
    __shared__ float lc[256];
    if (threadIdx.x < 256) lc[threadIdx.x] = code[threadIdx.x];
    __syncthreads();
    const int total = (N_TOTAL / 4) * K_TOTAL;   // 16,777,216 int4 groups
    const int stride = gridDim.x * blockDim.x;
    for (int i = blockIdx.x * blockDim.x + threadIdx.x; i < total; i += stride) {
        int4 v = reinterpret_cast<const int4*>(q)[i];
        float a = am[i >> 10];                   // one quant block == one weight row
        ushort4 o;
        o.x = f2bf(lc[v.x & 255] * a);
        o.y = f2bf(lc[v.y & 255] * a);
        o.z = f2bf(lc[v.z & 255] * a);
        o.w = f2bf(lc[v.w & 255] * a);
        reinterpret_cast<ushort4*>(wb)[i] = o;
    }
}

// ---------------- convert x fp32 -> bf16 ----------------
__global__ void cvt_x_kernel(const float* __restrict__ x,
                             unsigned short* __restrict__ xb) {
    const int total = (M_TOTAL * K_TOTAL) / 4;
    const int stride = gridDim.x * blockDim.x;
    for (int i = blockIdx.x * blockDim.x + threadIdx.x; i < total; i += stride) {
        float4 v = reinterpret_cast<const float4*>(x)[i];
        ushort4 o;
        o.x = f2bf(v.x); o.y = f2bf(v.y); o.z = f2bf(v.z); o.w = f2bf(v.w);
        reinterpret_cast<ushort4*>(xb)[i] = o;
    }
}

// ---------------- GEMM 256x256x64, 8-phase, swizzled LDS (m201 template) ----------
// ds-load frag macros: logical slot = ks*4 + (lane>>4); physical = ^ (lane&7)
#define LOAD_A(BUFI, MH)                                                          \
    UNROLL for (int mf = 0; mf < 4; ++mf)                                         \
        UNROLL for (int ks = 0; ks < 2; ++ks)                                     \
            a_r[mf][ks] = *reinterpret_cast<const bf16x8*>(                       \
                &sA[BUFI][((MH)*128 + arow_base + mf*16)*BK +                     \
                          (((ks*4 + rslot_hi) ^ rslot_xor)*8)]);

#define LOAD_B(BUFI, NH)                                                          \
    UNROLL for (int nf = 0; nf < 2; ++nf)                                         \
        UNROLL for (int ks = 0; ks < 2; ++ks)                                     \
            b_r[nf][ks] = *reinterpret_cast<const bf16x8*>(                       \
                &sB[BUFI][((NH)*128 + brow_base + nf*16)*BK +                     \
                          (((ks*4 + rslot_hi) ^ rslot_xor)*8)]);

#define DO_MFMA(MH, NH)                                                           \
    UNROLL for (int mf = 0; mf < 4; ++mf)                                         \
        UNROLL for (int nf = 0; nf < 2; ++nf) {                                   \
            acc[MH][mf][NH][nf] = __builtin_amdgcn_mfma_f32_16x16x32_bf16(        \
                a_r[mf][0], b_r[nf][0], acc[MH][mf][NH][nf], 0, 0, 0);            \
            acc[MH][mf][NH][nf] = __builtin_amdgcn_mfma_f32_16x16x32_bf16(        \
                a_r[mf][1], b_r[nf][1], acc[MH][mf][NH][nf], 0, 0, 0);            \
        }

// m201 form: NO sched_barrier here — frag loads are compiler-visible, so the
// compiler emits fine-grained lgkmcnt(N) per MFMA and may hoist MFMAs above the
// full drain (rule 18 only applies to inline-asm ds_reads). The asm is kept as
// a compiler memory fence (no load sinking / LDS value caching across phases).
#define PHASE_MID()                                                               \
    __builtin_amdgcn_s_barrier();                                                 \
    asm volatile("s_waitcnt lgkmcnt(0)" ::: "memory");                            \
    __builtin_amdgcn_s_setprio(1);

#define PHASE_END()                                                               \
    __builtin_amdgcn_s_setprio(0);                                                \
    __builtin_amdgcn_s_barrier();

__global__ __launch_bounds__(512, 2) void gemm8_kernel(
        const unsigned short* __restrict__ A,   // [M][K] bf16
        const unsigned short* __restrict__ B,   // [N][K] bf16
        const float* __restrict__ bias,         // [N]
        float* __restrict__ C) {                // [M][N] f32
    __shared__ __align__(16) unsigned short sA[2][BM * BK];   // 2 x 32 KB
    __shared__ __align__(16) unsigned short sB[2][BN * BK];   // 2 x 32 KB

    // XCD swizzle (nwg = 2048, % 8 == 0 -> bijective)
    const int nwg = gridDim.x;
    const int bid = blockIdx.x;
    const int wg  = (bid & 7) * (nwg >> 3) + (bid >> 3);
    const int nbn = N_TOTAL / BN;            // 64
    const int brow = (wg / nbn) * BM;
    const int bcol = (wg % nbn) * BN;

    const int tid  = threadIdx.x;
    const int wid  = tid >> 6;               // 0..7
    const int lane = tid & 63;
    const int wm   = wid >> 2;               // 0..1  (M-waves)
    const int wn   = wid & 3;                // 0..3  (N-waves)

    // ---- staging constants: linear LDS dest + pre-swizzled global source ----
    // issue(h,j) covers tile rows [h*128+j*64, +64); wave wid owns 8 rows.
    const int srow = wid * 8 + (lane >> 3);                 // row within issue
    const int scol = ((lane & 7) ^ (lane >> 3)) * 8;        // pre-swizzled col (elems)
    const unsigned short* Asrc = A + (long long)(brow + srow) * K_TOTAL + scol;
    const unsigned short* Bsrc = B + (long long)(bcol + srow) * K_TOTAL + scol;

    auto stA = [&](int h, int j, int kt, int b) {
        gload_lds16(Asrc + (long long)(h*128 + j*64) * K_TOTAL + kt*BK,
                    &sA[b][(h*128 + j*64)*BK + wid*512]);
    };
    auto stB = [&](int h, int j, int kt, int b) {
        gload_lds16(Bsrc + (long long)(h*128 + j*64) * K_TOTAL + kt*BK,
                    &sB[b][(h*128 + j*64)*BK + wid*512]);
    };

    // ---- ds-read constants (swizzled read side of the involution) ----
    const int arow_base = wm * 64 + (lane & 15);   // + mh*128 + mf*16
    const int brow_base = wn * 32 + (lane & 15);   // + nh*128 + nf*16
    const int rslot_hi  = lane >> 4;
    const int rslot_xor = lane & 7;

    f32x4 acc[2][4][2][2];
    UNROLL for (int mh = 0; mh < 2; ++mh)
        UNROLL for (int mf = 0; mf < 4; ++mf)
            UNROLL for (int nh = 0; nh < 2; ++nh)
                UNROLL for (int nf = 0; nf < 2; ++nf)
                    acc[mh][mf][nh][nf] = (f32x4){0.f, 0.f, 0.f, 0.f};

    bf16x8 a_r[4][2];
    bf16x8 b_r[2][2];

    // ---- prologue: tile0 full -> buf0; Ah0(1), Bh1(1) -> buf1 (12 loads/wave) ----
    stA(0,0,0,0); stA(0,1,0,0); stA(1,0,0,0); stA(1,1,0,0);
    stB(0,0,0,0); stB(0,1,0,0); stB(1,0,0,0); stB(1,1,0,0);
    stA(0,0,1,1); stA(0,1,1,1);
    stB(1,0,1,1); stB(1,1,1,1);
    asm volatile("s_waitcnt vmcnt(4)" ::: "memory");   // tile0 landed
    __builtin_amdgcn_s_barrier();

    // ---- main loop: 2 K-tiles / iteration, 8 phases ----
    // quadrant order per tile: (0,0) (0,1) (1,1) (1,0)
    // stage plan: ph1 Ah1(t+1)->b1, ph2 Bh0(t+1)->b1, ph3 Ah0(t+2)->b0,
    //             ph4 Bh1(t+2)->b0, ph5 Ah1(t+2)->b0, ph6 Bh0(t+2)->b0,
    //             ph7 Ah0(t+3)->b1, ph8 Bh1(t+3)->b1.  vmcnt(4) at ph4, ph8.
    for (int it = 0; it < NKT/2; ++it) {
        const int t   = 2*it;
        const int tp1 = t + 1;
        const int p2  = (t+2 < NKT) ? t+2 : NKT-1;   // tail: redundant reload, unread
        const int p3  = (t+3 < NKT) ? t+3 : NKT-1;

        // ph1 (buf0, tile t, quad 0,0)
        LOAD_A(0, 0); LOAD_B(0, 0);
        stA(1,0,tp1,1); stA(1,1,tp1,1);
        PHASE_MID(); DO_MFMA(0, 0); PHASE_END();

        // ph2 (0,1)
        LOAD_B(0, 1);
        stB(0,0,tp1,1); stB(0,1,tp1,1);
        PHASE_MID(); DO_MFMA(0, 1); PHASE_END();

        // ph3 (1,1)
        LOAD_A(0, 1);
        stA(0,0,p2,0); stA(0,1,p2,0);
        PHASE_MID(); DO_MFMA(1, 1); PHASE_END();

        // ph4 (1,0) -- tile t done; ensure tile t+1 (prologue/ph1/ph2 loads) landed
        LOAD_B(0, 0);
        stB(1,0,p2,0); stB(1,1,p2,0);
        PHASE_MID(); DO_MFMA(1, 0);
        __builtin_amdgcn_s_setprio(0);
        asm volatile("s_waitcnt vmcnt(4)" ::: "memory");
        __builtin_amdgcn_s_barrier();

        // ph5 (buf1, tile t+1, quad 0,0)
        LOAD_A(1, 0); LOAD_B(1, 0);
        stA(1,0,p2,0); stA(1,1,p2,0);
        PHASE_MID(); DO_MFMA(0, 0); PHASE_END();

        // ph6 (0,1)
        LOAD_B(1, 1);
        stB(0,0,p2,0); stB(0,1,p2,0);
        PHASE_MID(); DO_MFMA(0, 1); PHASE_END();

        // ph7 (1,1)
        LOAD_A(1, 1);
        stA(0,0,p3,1); stA(0,1,p3,1);
        PHASE_MID(); DO_MFMA(1, 1); PHASE_END();

        // ph8 (1,0) -- tile t+1 done; ensure tile t+2 (ph3..ph6 loads) landed
        LOAD_B(1, 0);
        stB(1,0,p3,1); stB(1,1,p3,1);
        PHASE_MID(); DO_MFMA(1, 0);
        __builtin_amdgcn_s_setprio(0);
        asm volatile("s_waitcnt vmcnt(4)" ::: "memory");
        __builtin_amdgcn_s_barrier();
    }

    // ---- epilogue: C/D layout col = lane&15, row = (lane>>4)*4 + r ----
    const int crow0 = (lane >> 4) * 4;
    const int ccol  = lane & 15;
    UNROLL for (int mh = 0; mh < 2; ++mh)
        UNROLL for (int mf = 0; mf < 4; ++mf) {
            const long long row0 = (long long)brow + mh*128 + wm*64 + mf*16 + crow0;
            UNROLL for (int nh = 0; nh < 2; ++nh)
                UNROLL for (int nf = 0; nf < 2; ++nf) {
                    const int col = bcol + nh*128 + wn*32 + nf*16 + ccol;
                    const float bv = bias[col];
                    UNROLL for (int r = 0; r < 4; ++r)
                        C[(row0 + r) * N_TOTAL + col] = acc[mh][mf][nh][nf][r] + bv;
                }
        }
}

extern "C" void kernel_launch(void* const* d_in, const int* in_sizes, int n_in,
                              void* d_out, int out_size, void* d_ws, size_t ws_size,
                              hipStream_t stream) {
    const float* x      = (const float*)d_in[0];   // [4,2048,4096] f32
    const int*   wq     = (const int*)  d_in[1];   // [16384,4096] int32 idx
    const float* absmax = (const float*)d_in[2];   // [16384]
    const float* code   = (const float*)d_in[3];   // [256]
    const float* bias   = (const float*)d_in[4];   // [16384]
    float* out = (float*)d_out;                    // [4,2048,16384] f32

    unsigned short* wb = (unsigned short*)d_ws;                    // W bf16 134 MB
    unsigned short* xb = wb + (size_t)N_TOTAL * K_TOTAL;           // x bf16  67 MB

    dequant_w_kernel<<<2048, 256, 0, stream>>>(wq, absmax, code, wb);
    cvt_x_kernel   <<<2048, 256, 0, stream>>>(x, xb);

    dim3 grid((M_TOTAL / BM) * (N_TOTAL / BN));    // 32*64 = 2048 blocks
    gemm8_kernel<<<grid, 512, 0, stream>>>(xb, wb, bias, out);
}